// Round 1
// 335.194 us; speedup vs baseline: 1.0767x; 1.0767x over previous
//
#include <hip/hip_runtime.h>
#include <hip/hip_bf16.h>

typedef __hip_bfloat16 bf16;
typedef unsigned short u16;
typedef float f32x2 __attribute__((ext_vector_type(2)));

#define NC 8192
#define NF 32768
#define KNN 16
#define FMAXV 3.402823466e+38f

__device__ __forceinline__ float bfbits2f(u16 u){
  union { unsigned u; float f; } x; x.u = ((unsigned)u) << 16; return x.f;
}
__device__ __forceinline__ float asfloat(unsigned u){
  union { unsigned u; float f; } x; x.u = u; return x.f;
}
// packed fp32 fma: d = a*b + c on both halves (IEEE fma per half, bit-exact vs fmaf)
__device__ __forceinline__ f32x2 pk_fma(f32x2 a, f32x2 b, f32x2 c){
  f32x2 d;
  asm("v_pk_fma_f32 %0, %1, %2, %3" : "=v"(d) : "v"(a), "v"(b), "v"(c));
  return d;
}

// ---------- k_prep: paired-candidate pos layout + MLP weight swizzles (grid 64 x 256 = 16384) ----------
// posP[2q]   = (x_{2q}, x_{2q+1}, y_{2q}, y_{2q+1})
// posP[2q+1] = (z_{2q}, z_{2q+1}, w_{2q}, w_{2q+1})   w = |d|^2/2
__global__ __launch_bounds__(256) void k_prep(const float* __restrict__ dpos,
                                              const float* __restrict__ W1,
                                              const float* __restrict__ W2,
                                              float4* __restrict__ posP,
                                              float4* __restrict__ W1eSa,
                                              float4* __restrict__ W1eSb,
                                              float4* __restrict__ W2Sa,
                                              float4* __restrict__ W2Sb){
  int g = blockIdx.x * 256 + threadIdx.x;
  if (g < 4096){
    const float2* dp2 = (const float2*)(dpos + (size_t)g * 6);
    float2 a = dp2[0], b = dp2[1], c = dp2[2];
    float x0 = a.x, y0 = a.y, z0 = b.x;
    float x1 = b.y, y1 = c.x, z1 = c.y;
    float dd0 = __fadd_rn(__fadd_rn(__fmul_rn(x0,x0), __fmul_rn(y0,y0)), __fmul_rn(z0,z0));
    float dd1 = __fadd_rn(__fadd_rn(__fmul_rn(x1,x1), __fmul_rn(y1,y1)), __fmul_rn(z1,z1));
    posP[g * 2]     = make_float4(x0, x1, y0, y1);
    posP[g * 2 + 1] = make_float4(z0, z1, dd0 * 0.5f, dd1 * 0.5f);
  } else if (g >= 8192 && g < 10240){
    int f = g - 8192; int c4 = f >> 6, jg = f & 63;
    W1eSa[f] = ((const float4*)(W1 + (size_t)(2 * jg) * 384 + 256))[c4];
  } else if (g >= 10240 && g < 12288){
    int f = g - 10240; int c4 = f >> 6, jg = f & 63;
    W1eSb[f] = ((const float4*)(W1 + (size_t)(2 * jg + 1) * 384 + 256))[c4];
  } else if (g >= 12288 && g < 14336){
    int f = g - 12288; int c4 = f >> 6, jg = f & 63;
    W2Sa[f] = ((const float4*)(W2 + (size_t)(2 * jg) * 128))[c4];
  } else if (g >= 14336){
    int f = g - 14336; int c4 = f >> 6, jg = f & 63;
    W2Sb[f] = ((const float4*)(W2 + (size_t)(2 * jg + 1) * 128))[c4];
  }
}

// ---------- k_wprod: weight-product fold (exact associativity rewrite) ----------
__global__ __launch_bounds__(256) void k_wprod(const float* __restrict__ Wk,
                                               const float* __restrict__ Wv,
                                               const float* __restrict__ Wq,
                                               const float* __restrict__ W1,
                                               const float* __restrict__ bk,
                                               const float* __restrict__ bv,
                                               const float* __restrict__ bq,
                                               float* __restrict__ WkqS,
                                               float* __restrict__ WvuS,
                                               float* __restrict__ bkq,
                                               float* __restrict__ bvu,
                                               float* __restrict__ wbq,
                                               float* __restrict__ sbq){
  __shared__ float red[256];
  int b = blockIdx.x, t = threadIdx.x;
  if (b < 128){
    int c = b;
    float acc = 0.f;
    for (int j = 0; j < 256; ++j)
      acc = fmaf(Wk[(size_t)j * 256 + t], Wq[(size_t)j * 128 + c], acc);
    WkqS[(size_t)((t >> 2) * 128 + c) * 4 + (t & 3)] = acc;
    red[t] = bk[t] * Wq[(size_t)t * 128 + c];
    __syncthreads();
    for (int s = 128; s > 0; s >>= 1){ if (t < s) red[t] += red[t + s]; __syncthreads(); }
    if (t == 0) bkq[c] = red[0];
  } else if (b < 256){
    int h = b - 128;
    float acc = 0.f;
    for (int c2 = 0; c2 < 256; ++c2)
      acc = fmaf(Wv[(size_t)c2 * 256 + t], W1[(size_t)h * 384 + c2], acc);
    WvuS[(size_t)((t >> 2) * 128 + h) * 4 + (t & 3)] = acc;
    red[t] = bv[t] * W1[(size_t)h * 384 + t];
    __syncthreads();
    for (int s = 128; s > 0; s >>= 1){ if (t < s) red[t] += red[t + s]; __syncthreads(); }
    if (t == 0) bvu[h] = red[0];
  } else {
    float acc = 0.f;
    for (int j = 0; j < 256; ++j)
      acc = fmaf(Wk[(size_t)j * 256 + t], bq[j], acc);
    wbq[t] = acc;
    red[t] = bk[t] * bq[t];
    __syncthreads();
    for (int s = 128; s > 0; s >>= 1){ if (t < s) red[t] += red[t + s]; __syncthreads(); }
    if (t == 0) sbq[0] = red[0];
  }
}

// ---------- k_dec: Zd = df@Wkq + bkq, Ud = df@Wvu + bvu, bqK = df@wbq + sbq ----------
__global__ __launch_bounds__(256) void k_dec(const float* __restrict__ df,
                                             const float4* __restrict__ WkqS,
                                             const float4* __restrict__ WvuS,
                                             const float* __restrict__ bkq,
                                             const float* __restrict__ bvu,
                                             const float* __restrict__ wbq,
                                             const float* __restrict__ sbq,
                                             bf16* __restrict__ Zd, bf16* __restrict__ Ud,
                                             float* __restrict__ bqK){
  __shared__ float part[16][16];
  int t = threadIdx.x;
  int g0 = blockIdx.x * 16;
  int half = __builtin_amdgcn_readfirstlane(t >> 7);
  int c = t & 127;
  const float4* W = half ? WvuS : WkqS;
  float acc[16];
  #pragma unroll
  for (int p = 0; p < 16; ++p) acc[p] = 0.f;
  for (int j4 = 0; j4 < 64; ++j4){
    float4 w = W[j4 * 128 + c];
    #pragma unroll
    for (int p = 0; p < 16; ++p){
      float4 a = ((const float4*)(df + (size_t)(g0 + p) * 256))[j4];
      acc[p] += w.x*a.x + w.y*a.y + w.z*a.z + w.w*a.w;
    }
  }
  float bias = half ? bvu[c] : bkq[c];
  bf16* dst = half ? Ud : Zd;
  #pragma unroll
  for (int p = 0; p < 16; ++p)
    dst[(size_t)(g0 + p) * 128 + c] = __float2bfloat16(acc[p] + bias);
  {
    int r = t >> 4, seg = t & 15;
    float s = 0.f;
    const float* dr = df + (size_t)(g0 + r) * 256 + seg * 16;
    const float* wq = wbq + seg * 16;
    #pragma unroll
    for (int e = 0; e < 16; ++e) s = fmaf(dr[e], wq[e], s);
    part[r][seg] = s;
  }
  __syncthreads();
  if (t < 16){
    float s = sbq[0];
    #pragma unroll
    for (int seg = 0; seg < 16; ++seg) s += part[t][seg];
    bqK[g0 + t] = s;
  }
}

// ---------- fused KNN + attention: 8 points/block, candidates split across 4 waves ----------
// Pass A/B distance core uses v_pk_fma_f32 on candidate pairs (bit-exact vs scalar fmaf chain).
// Score phase: parallel over k (lane = part*16 + k), ef row staged in LDS (reuses smin).
__global__ __launch_bounds__(256) void k_attn(const float* __restrict__ epos,
                                              const float4* __restrict__ posP,
                                              const float* __restrict__ ef,
                                              const bf16* __restrict__ Zd,
                                              const bf16* __restrict__ Ud,
                                              const float* __restrict__ bqK,
                                              bf16* __restrict__ hagg){
  __shared__ float smin[8 * 64];
  __shared__ float tauLDS[8];
  __shared__ int   cnt[8];
  __shared__ float lval[8][64];
  __shared__ int   lidx[8][64];

  int t = threadIdx.x, lane = t & 63, w = t >> 6;
  int n0 = blockIdx.x * 8;
  f32x2 nex2[8], ney2[8], nez2[8];
  #pragma unroll
  for (int p = 0; p < 8; ++p){
    float nx = -epos[(n0 + p) * 3 + 0];
    float ny = -epos[(n0 + p) * 3 + 1];
    float nz = -epos[(n0 + p) * 3 + 2];
    nex2[p].x = nx; nex2[p].y = nx;
    ney2[p].x = ny; ney2[p].y = ny;
    nez2[p].x = nz; nez2[p].y = nz;
  }
  const float4* base = posP + w * 2048;   // wave's 1024 candidate-pairs = 2048 float4

  // PASS A: per-lane minima over 2 packed candidates/iter (3 pk_fma + 2 min per point)
  f32x2 vmin2[8];
  #pragma unroll
  for (int p = 0; p < 8; ++p){ vmin2[p].x = FMAXV; vmin2[p].y = FMAXV; }
  #pragma unroll 2
  for (int s = 0; s < 16; ++s){
    int q2 = (s * 64 + lane) * 2;
    float4 XY = base[q2], ZW = base[q2 + 1];
    f32x2 X = {XY.x, XY.y}, Y = {XY.z, XY.w}, Z = {ZW.x, ZW.y}, W = {ZW.z, ZW.w};
    #pragma unroll
    for (int p = 0; p < 8; ++p){
      f32x2 v2 = pk_fma(nex2[p], X, W);
      v2 = pk_fma(ney2[p], Y, v2);
      v2 = pk_fma(nez2[p], Z, v2);
      vmin2[p].x = fminf(vmin2[p].x, v2.x);
      vmin2[p].y = fminf(vmin2[p].y, v2.y);
    }
  }
  float vmin[8];
  #pragma unroll
  for (int p = 0; p < 8; ++p) vmin[p] = fminf(vmin2[p].x, vmin2[p].y);

  // bitonic sort of 64 lane-minima, 8 point-registers at once
  #pragma unroll
  for (int k = 2; k <= 64; k <<= 1){
    #pragma unroll
    for (int j = k >> 1; j > 0; j >>= 1){
      bool keepmin = ((lane & j) == 0) == ((lane & k) == 0);
      #pragma unroll
      for (int p = 0; p < 8; ++p){
        float pv = __shfl_xor(vmin[p], j);
        vmin[p] = keepmin ? fminf(vmin[p], pv) : fmaxf(vmin[p], pv);
      }
    }
  }
  if (lane < 16){
    #pragma unroll
    for (int p = 0; p < 8; ++p) smin[p * 64 + w * 16 + lane] = vmin[p];
  }
  if (t < 8) cnt[t] = 0;
  __syncthreads();
  // wave w sorts unions for points 2w, 2w+1; tau0 = 17th smallest
  #pragma unroll
  for (int u = 0; u < 2; ++u){
    int p = w * 2 + u;
    float v = smin[p * 64 + lane];
    #pragma unroll
    for (int k = 2; k <= 64; k <<= 1){
      #pragma unroll
      for (int j = k >> 1; j > 0; j >>= 1){
        float pv = __shfl_xor(v, j);
        bool keepmin = ((lane & j) == 0) == ((lane & k) == 0);
        v = keepmin ? fminf(v, pv) : fmaxf(v, pv);
      }
    }
    if (lane == 16) tauLDS[p] = v;
  }
  __syncthreads();
  float tau0[8];
  #pragma unroll
  for (int p = 0; p < 8; ++p) tau0[p] = tauLDS[p];

  // PASS B: filtered append (identical packed val expression)
  #pragma unroll 2
  for (int s = 0; s < 16; ++s){
    int q = s * 64 + lane;
    float4 XY = base[q * 2], ZW = base[q * 2 + 1];
    f32x2 X = {XY.x, XY.y}, Y = {XY.z, XY.w}, Z = {ZW.x, ZW.y}, W = {ZW.z, ZW.w};
    int cand0 = w * 2048 + q * 2;
    #pragma unroll
    for (int p = 0; p < 8; ++p){
      f32x2 v2 = pk_fma(nex2[p], X, W);
      v2 = pk_fma(ney2[p], Y, v2);
      v2 = pk_fma(nez2[p], Z, v2);
      if (v2.x <= tau0[p]){
        int slot = atomicAdd(&cnt[p], 1);
        if (slot < 64){ lval[p][slot] = v2.x; lidx[p][slot] = cand0; }
      }
      if (v2.y <= tau0[p]){
        int slot = atomicAdd(&cnt[p], 1);
        if (slot < 64){ lval[p][slot] = v2.y; lidx[p][slot] = cand0 + 1; }
      }
    }
  }
  __syncthreads();

  // wave w finalizes points 2w, 2w+1: exact (val,idx) sort, parallel-k scores, softmax, agg
  for (int u = 0; u < 2; ++u){
    int p = w * 2 + u;
    int n = n0 + p;
    int c = cnt[p]; if (c > 64) c = 64;
    float v  = (lane < c) ? lval[p][lane] : FMAXV;
    int   id = (lane < c) ? lidx[p][lane] : 0x7fffffff;
    #pragma unroll
    for (int k = 2; k <= 64; k <<= 1){
      #pragma unroll
      for (int j = k >> 1; j > 0; j >>= 1){
        float pv  = __shfl_xor(v, j);
        int   pid = __shfl_xor(id, j);
        bool keepmin = ((lane & j) == 0) == ((lane & k) == 0);
        bool pless = (pv < v) || (pv == v && pid < id);
        bool take = keepmin ? pless : !pless;
        if (take){ v = pv; id = pid; }
      }
    }
    int topi = id;

    // stage ef row into LDS (smin region is dead past this point; wave-private 128 floats)
    *(float2*)&smin[w * 128 + lane * 2] = *(const float2*)(ef + (size_t)n * 128 + lane * 2);
    asm volatile("s_waitcnt lgkmcnt(0)" ::: "memory");

    // lane = part*16 + k: 32-dim partial dot of ef x Zd[ik], reduce over 4 parts
    int kk = lane & 15, part = lane >> 4;
    int ik = __shfl(topi, kk);
    const uint4*  zr = (const uint4*)((const u16*)Zd + (size_t)ik * 128) + part * 4;
    const float4* e4 = (const float4*)(smin + w * 128) + part * 8;
    float pr = 0.f;
    #pragma unroll
    for (int i = 0; i < 4; ++i){
      uint4 z = zr[i];
      float4 ea = e4[2 * i], eb = e4[2 * i + 1];
      pr = fmaf(ea.x, asfloat(z.x << 16), pr); pr = fmaf(ea.y, asfloat(z.x & 0xffff0000u), pr);
      pr = fmaf(ea.z, asfloat(z.y << 16), pr); pr = fmaf(ea.w, asfloat(z.y & 0xffff0000u), pr);
      pr = fmaf(eb.x, asfloat(z.z << 16), pr); pr = fmaf(eb.y, asfloat(z.z & 0xffff0000u), pr);
      pr = fmaf(eb.z, asfloat(z.w << 16), pr); pr = fmaf(eb.w, asfloat(z.w & 0xffff0000u), pr);
    }
    pr += __shfl_xor(pr, 16);
    pr += __shfl_xor(pr, 32);
    float sc = (pr + bqK[ik]) * (1.0f / 16.0f);   // replicated across the 4 parts

    float mx = sc;
    #pragma unroll
    for (int off = 8; off >= 1; off >>= 1) mx = fmaxf(mx, __shfl_xor(mx, off));
    float e = (lane < KNN) ? __expf(sc - mx) : 0.f;
    float l = e;
    #pragma unroll
    for (int off = 8; off >= 1; off >>= 1) l += __shfl_xor(l, off);
    float wgt = (lane < KNN) ? (e / l) : 0.f;

    float a0 = 0.f, a1 = 0.f;
    #pragma unroll
    for (int k = 0; k < KNN; ++k){
      int ikk = __shfl(topi, k);
      float wk = __shfl(wgt, k);
      ushort2 uu = *(const ushort2*)((const u16*)Ud + (size_t)ikk * 128 + lane * 2);
      a0 = fmaf(wk, bfbits2f(uu.x), a0);
      a1 = fmaf(wk, bfbits2f(uu.y), a1);
    }
    bf16 h0 = __float2bfloat16(a0), h1 = __float2bfloat16(a1);
    ushort2 st; st.x = *(u16*)&h0; st.y = *(u16*)&h1;
    *(ushort2*)(hagg + (size_t)n * 128 + lane * 2) = st;
  }
}

// ---------- fused MLP: h = relu(hagg + W1e@ef + b1) -> LDS; up = W2@h + b2; LN; out + tail ----------
__global__ __launch_bounds__(256) void k_mlp(const bf16* __restrict__ hagg,
                                             const float* __restrict__ ef,
                                             const float4* __restrict__ W1eSa,
                                             const float4* __restrict__ W1eSb,
                                             const float* __restrict__ b1,
                                             const float4* __restrict__ W2Sa,
                                             const float4* __restrict__ W2Sb,
                                             const float* __restrict__ b2,
                                             const float* __restrict__ lng, const float* __restrict__ lnb,
                                             const float* __restrict__ epos, const int* __restrict__ lab,
                                             float* __restrict__ out){
  __shared__ float hbuf[16 * 128];
  __shared__ float ubuf[16 * 128];
  __shared__ float stats[32];
  int t = threadIdx.x;
  int n0 = blockIdx.x * 16;
  {
    int gid = blockIdx.x * 256 + t;
    if (gid < NF){
      float* op = out + (size_t)NF * 128;
      op[gid * 3 + 0] = epos[gid * 3 + 0];
      op[gid * 3 + 1] = epos[gid * 3 + 1];
      op[gid * 3 + 2] = epos[gid * 3 + 2];
      out[(size_t)NF * 128 + (size_t)NF * 3 + gid] = (float)lab[gid];
    }
  }
  int jg = t & 63;
  int pg4 = __builtin_amdgcn_readfirstlane((t >> 6) * 4);
  int j0 = jg * 2;
  float acc[2][4];
  #pragma unroll
  for (int a = 0; a < 2; ++a)
    #pragma unroll
    for (int p = 0; p < 4; ++p) acc[a][p] = 0.f;
  for (int c4 = 0; c4 < 32; ++c4){
    float4 wa = W1eSa[c4 * 64 + jg];
    float4 wb = W1eSb[c4 * 64 + jg];
    #pragma unroll
    for (int p = 0; p < 4; ++p){
      float4 x = ((const float4*)(ef + (size_t)(n0 + pg4 + p) * 128))[c4];
      acc[0][p] += wa.x*x.x + wa.y*x.y + wa.z*x.z + wa.w*x.w;
      acc[1][p] += wb.x*x.x + wb.y*x.y + wb.z*x.z + wb.w*x.w;
    }
  }
  float b1a = b1[j0], b1b = b1[j0 + 1];
  #pragma unroll
  for (int p = 0; p < 4; ++p){
    size_t row = (size_t)(n0 + pg4 + p);
    ushort2 hgv = *(const ushort2*)((const u16*)hagg + row * 128 + j0);
    hbuf[(pg4 + p) * 128 + j0]     = fmaxf(acc[0][p] + b1a + bfbits2f(hgv.x), 0.f);
    hbuf[(pg4 + p) * 128 + j0 + 1] = fmaxf(acc[1][p] + b1b + bfbits2f(hgv.y), 0.f);
  }
  __syncthreads();
  float acc2[2][4];
  #pragma unroll
  for (int a = 0; a < 2; ++a)
    #pragma unroll
    for (int p = 0; p < 4; ++p) acc2[a][p] = 0.f;
  const float4* hb4 = (const float4*)hbuf;
  for (int c4 = 0; c4 < 32; ++c4){
    float4 wa = W2Sa[c4 * 64 + jg];
    float4 wb = W2Sb[c4 * 64 + jg];
    #pragma unroll
    for (int p = 0; p < 4; ++p){
      float4 x = hb4[(pg4 + p) * 32 + c4];
      acc2[0][p] += wa.x*x.x + wa.y*x.y + wa.z*x.z + wa.w*x.w;
      acc2[1][p] += wb.x*x.x + wb.y*x.y + wb.z*x.z + wb.w*x.w;
    }
  }
  float b2a = b2[j0], b2b = b2[j0 + 1];
  float u[2][4];
  #pragma unroll
  for (int p = 0; p < 4; ++p){
    u[0][p] = acc2[0][p] + b2a;
    u[1][p] = acc2[1][p] + b2b;
    ubuf[(pg4 + p) * 128 + j0]     = u[0][p];
    ubuf[(pg4 + p) * 128 + j0 + 1] = u[1][p];
  }
  __syncthreads();
  {
    int p = t >> 4, qi = t & 15;
    const float* ub = &ubuf[p * 128 + qi * 8];
    float s = 0.f, s2 = 0.f;
    #pragma unroll
    for (int e2i = 0; e2i < 8; ++e2i){ float v = ub[e2i]; s += v; s2 += v * v; }
    #pragma unroll
    for (int off = 1; off < 16; off <<= 1){ s += __shfl_xor(s, off); s2 += __shfl_xor(s2, off); }
    if (qi == 0){
      float mu = s * (1.f / 128.f);
      float var = s2 * (1.f / 128.f) - mu * mu;
      stats[p] = mu;
      stats[16 + p] = rsqrtf(fmaxf(var, 0.f) + 1e-5f);
    }
  }
  __syncthreads();
  float ga = lng[j0], gb = lng[j0 + 1];
  float ba = lnb[j0], bbv = lnb[j0 + 1];
  #pragma unroll
  for (int p = 0; p < 4; ++p){
    float mu = stats[pg4 + p], rs = stats[16 + pg4 + p];
    out[(size_t)(n0 + pg4 + p) * 128 + j0]     = (u[0][p] - mu) * rs * ga + ba;
    out[(size_t)(n0 + pg4 + p) * 128 + j0 + 1] = (u[1][p] - mu) * rs * gb + bbv;
  }
}

extern "C" void kernel_launch(void* const* d_in, const int* in_sizes, int n_in,
                              void* d_out, int out_size, void* d_ws, size_t ws_size,
                              hipStream_t stream){
  const float* df   = (const float*)d_in[0];
  const float* dpos = (const float*)d_in[1];
  const float* ef   = (const float*)d_in[2];
  const float* epos = (const float*)d_in[3];
  const int*   lab  = (const int*)d_in[4];
  const float* Wq = (const float*)d_in[5];
  const float* bq = (const float*)d_in[6];
  const float* Wk = (const float*)d_in[7];
  const float* bk = (const float*)d_in[8];
  const float* Wv = (const float*)d_in[9];
  const float* bv = (const float*)d_in[10];
  const float* W1 = (const float*)d_in[11];
  const float* b1 = (const float*)d_in[12];
  const float* W2 = (const float*)d_in[13];
  const float* b2 = (const float*)d_in[14];
  const float* lng = (const float*)d_in[15];
  const float* lnb = (const float*)d_in[16];
  float* out = (float*)d_out;

  // workspace layout (~12.6 MB)
  char* wsb = (char*)d_ws;
  float4* posP  = (float4*)(wsb);                    // 128 KB
  bf16*   Zd    = (bf16*)(wsb + 131072);             // 2 MB
  bf16*   Ud    = (bf16*)(wsb + 2228224);            // 2 MB
  float*  bqK   = (float*)(wsb + 4325376);           // 32 KB
  bf16*   hagg  = (bf16*)(wsb + 4358144);            // 8 MB
  float4* W1eSa = (float4*)(wsb + 12746752);         // 32 KB
  float4* W1eSb = (float4*)(wsb + 12779520);         // 32 KB
  float4* W2Sa  = (float4*)(wsb + 12812288);         // 32 KB
  float4* W2Sb  = (float4*)(wsb + 12845056);         // 32 KB
  float*  WkqS  = (float*)(wsb + 12877824);          // 128 KB
  float*  WvuS  = (float*)(wsb + 13008896);          // 128 KB
  float*  bkq   = (float*)(wsb + 13139968);          // 512 B
  float*  bvu   = (float*)(wsb + 13140480);          // 512 B
  float*  wbq   = (float*)(wsb + 13140992);          // 1 KB
  float*  sbq   = (float*)(wsb + 13142016);          // 4 B

  k_prep  <<<64,  256, 0, stream>>>(dpos, W1, W2, posP, W1eSa, W1eSb, W2Sa, W2Sb);
  k_wprod <<<257, 256, 0, stream>>>(Wk, Wv, Wq, W1, bk, bv, bq, WkqS, WvuS, bkq, bvu, wbq, sbq);
  k_dec   <<<NC / 16, 256, 0, stream>>>(df, (const float4*)WkqS, (const float4*)WvuS, bkq, bvu, wbq, sbq, Zd, Ud, bqK);
  k_attn  <<<NF / 8, 256, 0, stream>>>(epos, posP, ef, Zd, Ud, bqK, hagg);
  k_mlp   <<<NF / 16, 256, 0, stream>>>(hagg, ef, W1eSa, W1eSb, b1, W2Sa, W2Sb, b2, lng, lnb, epos, lab, out);
  (void)in_sizes; (void)n_in; (void)out_size; (void)ws_size;
}